// Round 5
// baseline (498.755 us; speedup 1.0000x reference)
//
#include <hip/hip_runtime.h>
#include <stdint.h>

#define NB    512
#define CIN   12
#define TIN   5000
#define T1    496
#define T2    95

// workspace layout (float offsets)
#define OFS_STATS 0        // 256 floats: [bn1_sum 32][bn1_sq 32][bn2_sum 32][bn2_sq 32][unused]
#define OFS_W1P   256      // 12*50*32 = 19200, layout [ic][k][oc]
#define OFS_W2P   19456    // 32*25*32 = 25600, layout [ic][k][oc]
#define OFS_Y1    45056    // 512*32*496 = 8126464
#define OFS_Y2    8171520  // 512*32*95  = 1556480

#define GAS __attribute__((address_space(1)))
#define LAS __attribute__((address_space(3)))
// async global->LDS, 16B per lane, dest = wave-uniform base + lane*16
#define ASYNC_COPY16(gp, lp) \
    __builtin_amdgcn_global_load_lds((const GAS void*)(gp), (LAS void*)(lp), 16, 0, 0)

// ---------------- prep: zero stats + repack weights ----------------
__global__ void prep_kernel(const float* __restrict__ w1, const float* __restrict__ w2,
                            float* __restrict__ ws) {
    int idx = blockIdx.x * 256 + threadIdx.x;
    if (idx < 256) ws[idx] = 0.f;
    int j = idx - 256;
    if (j >= 0 && j < 19200) {            // w1p[ic][k][oc], oc fastest
        int ic = j / 1600, r = j % 1600, k = r / 32, oc = r % 32;
        ws[OFS_W1P + j] = w1[oc * 600 + ic * 50 + k];
    }
    int j2 = idx - 19456;
    if (j2 >= 0 && j2 < 25600) {          // w2p[ic][k][oc]
        int ic = j2 / 800, r = j2 % 800, k = r / 32, oc = r % 32;
        ws[OFS_W2P + j2] = w2[oc * 800 + ic * 25 + k];
    }
}

// ---------------- conv1 + bias, fused BN1 stats ----------------
// grid 1024: b = bx>>1, t-tile(256) = bx&1. block 128: ocg=tid&3 (8 oc), tg=tid>>2.
// t-map: thread (ocg,tg) handles t = t0 + tg + 32j (j=0..7) -> x LDS reads at
// 10*tg + 320j + k: 16 consecutive tg per wave, stride 10 vs 32 banks -> conflict-free
// with a LINEAR (unskewed) layout, which enables async global_load_lds staging
// (no VGPR round-trip, no prefetch-sinking: issue ic+1 AFTER the barrier so the
// barrier drain never waits on it; compute covers the latency).
__global__ __launch_bounds__(128, 2) void conv1_kernel(const float* __restrict__ x,
                                                       const float* __restrict__ b1,
                                                       float* __restrict__ ws) {
    const float* w1p = ws + OFS_W1P;
    float* y1 = ws + OFS_Y1;
    float* stats = ws + OFS_STATS;
    int b  = blockIdx.x >> 1;
    int t0 = (blockIdx.x & 1) * 256;
    int tid = threadIdx.x;
    int ocg = tid & 3, tg = tid >> 2;
    int oc0 = ocg * 8;
    int xoff = 10 * tg;

    __shared__ __align__(16) float xs_s[2][2600];
    __shared__ __align__(16) float ws_s[2][1600];
    __shared__ float sred[128];

    float acc[8][8];
#pragma unroll
    for (int a = 0; a < 8; ++a)
#pragma unroll
        for (int c = 0; c < 8; ++c) acc[a][c] = 0.f;

    const float* xb = x + (size_t)b * (CIN * TIN) + t0 * 10;
    const int nchunk = (t0 == 0) ? 650 : 610;   // in-bounds 16B chunks of the window
    const int wbase = tid & ~63;                // wave-uniform lane-block base

    if (t0 != 0) {   // zero the OOB tail once (DMA never touches it: chunks >= 610 masked)
        for (int i = tid; i < 160; i += 128) {
            xs_s[0][2440 + i] = 0.f;
            xs_s[1][2440 + i] = 0.f;
        }
    }

    auto issue = [&](int ic) {
        int buf = ic & 1;
        const float* xg = xb + ic * TIN;
#pragma unroll
        for (int c = 0; c < 6; ++c) {
            int i = c * 128 + tid;
            if (i < nchunk)
                ASYNC_COPY16(xg + 4 * i, &xs_s[buf][4 * (c * 128 + wbase)]);
        }
        const float* wg = w1p + ic * 1600;
#pragma unroll
        for (int c = 0; c < 4; ++c) {
            int i = c * 128 + tid;
            if (i < 400)
                ASYNC_COPY16(wg + 4 * i, &ws_s[buf][4 * (c * 128 + wbase)]);
        }
    };

    issue(0);
    for (int ic = 0; ic < CIN; ++ic) {
        const int cur = ic & 1;
        __syncthreads();                  // drains DMA -> buf[cur] ready; buf[1-cur] free
        if (ic + 1 < CIN) issue(ic + 1);  // flies during compute; next barrier drains it

#pragma unroll 1
        for (int m = 0; m < 5; ++m) {
#pragma unroll
            for (int u = 0; u < 5; ++u) {
                const int k = m * 10 + u * 2;
                const float* wr = &ws_s[cur][k * 32 + oc0];
                float4 w00 = *(const float4*)(wr);
                float4 w01 = *(const float4*)(wr + 4);
                float4 w10 = *(const float4*)(wr + 32);
                float4 w11 = *(const float4*)(wr + 36);
                float2 xv[8];
#pragma unroll
                for (int j = 0; j < 8; ++j)
                    xv[j] = *(const float2*)&xs_s[cur][xoff + 320 * j + k];
                float wk[8]  = {w00.x, w00.y, w00.z, w00.w, w01.x, w01.y, w01.z, w01.w};
                float wk1[8] = {w10.x, w10.y, w10.z, w10.w, w11.x, w11.y, w11.z, w11.w};
#pragma unroll
                for (int jo = 0; jo < 8; ++jo)
#pragma unroll
                    for (int j = 0; j < 8; ++j)
                        acc[jo][j] = fmaf(wk1[jo], xv[j].y, fmaf(wk[jo], xv[j].x, acc[jo][j]));
            }
        }
    }

    float bias[8];
#pragma unroll
    for (int jo = 0; jo < 8; ++jo) bias[jo] = b1[oc0 + jo];

    float psum[8], psq[8];
#pragma unroll
    for (int jo = 0; jo < 8; ++jo) { psum[jo] = 0.f; psq[jo] = 0.f; }
#pragma unroll
    for (int jo = 0; jo < 8; ++jo) {
        float* yrow = y1 + (size_t)(b * 32 + oc0 + jo) * T1 + t0 + tg;
#pragma unroll
        for (int j = 0; j < 8; ++j) {
            int trel = tg + 32 * j;
            if (t0 + trel < T1) {
                float v = acc[jo][j] + bias[jo];
                yrow[32 * j] = v;
                psum[jo] += v;
                psq[jo] = fmaf(v, v, psq[jo]);
            }
        }
    }
#pragma unroll
    for (int off = 32; off >= 4; off >>= 1) {
#pragma unroll
        for (int jo = 0; jo < 8; ++jo) {
            psum[jo] += __shfl_down(psum[jo], off, 64);
            psq[jo]  += __shfl_down(psq[jo],  off, 64);
        }
    }
    int lane = tid & 63, wvi = tid >> 6;
    if (lane < 4) {
#pragma unroll
        for (int jo = 0; jo < 8; ++jo) {
            sred[((wvi * 4 + lane) * 8 + jo) * 2 + 0] = psum[jo];
            sred[((wvi * 4 + lane) * 8 + jo) * 2 + 1] = psq[jo];
        }
    }
    __syncthreads();
    if (tid < 64) {
        int oc = tid >> 1, which = tid & 1;
        int og = oc >> 3, jo = oc & 7;
        float v = sred[((0 * 4 + og) * 8 + jo) * 2 + which] +
                  sred[((1 * 4 + og) * 8 + jo) * 2 + which];
        atomicAdd(&stats[which * 32 + oc], v);
    }
}

// ---------------- conv2 + BN1-fold + BN2 stats (fused; y2 out) ----------------
// grid 512 (b). block 256: ocg=tid&7 (4 oc), tg=tid>>3 (0..31, 3 t each, t<95 masked)
__global__ __launch_bounds__(256, 2) void conv2bn_kernel(const float* __restrict__ g1,
                                                         const float* __restrict__ be1,
                                                         const float* __restrict__ b2,
                                                         float* __restrict__ ws) {
    const float* w2p = ws + OFS_W2P;
    const float* y1 = ws + OFS_Y1;
    float* y2 = ws + OFS_Y2;
    float* stats = ws + OFS_STATS;
    int b = blockIdx.x, tid = threadIdx.x;
    int ocg = tid & 7, tg = tid >> 3;
    int oc0 = ocg * 4;

    __shared__ float s1s[32], sh1s[32];
    __shared__ __align__(16) float a1s[512];
    __shared__ __align__(16) float w2s[800];
    __shared__ float sred[256];

    float acc[4][3];
#pragma unroll
    for (int a = 0; a < 4; ++a)
#pragma unroll
        for (int c = 0; c < 3; ++c) acc[a][c] = 0.f;

    if (tid < 32) {   // BN1 scale/shift in-kernel (replaces bnstats kernel)
        float mean = stats[tid] * (1.f / 253952.f);
        float var  = stats[32 + tid] * (1.f / 253952.f) - mean * mean;
        float s = g1[tid] * rsqrtf(var + 1e-5f);
        s1s[tid] = s;
        sh1s[tid] = be1[tid] - mean * s;
    }

    float4 pa, pw2;
    auto fetch = [&](int ic) {
        if (tid < 124) pa  = *(const float4*)(y1 + (size_t)(b * 32 + ic) * T1 + 4 * tid);
        if (tid < 200) pw2 = *(const float4*)(w2p + ic * 800 + 4 * tid);
    };
    fetch(0);
    __syncthreads();   // s1s ready

#pragma unroll 1
    for (int ic = 0; ic < 32; ++ic) {
        float s1 = s1s[ic], sh1 = sh1s[ic];
        if (tid < 124) {
            float4 v = pa;
            v.x = fmaxf(fmaf(v.x, s1, sh1), 0.f);
            v.y = fmaxf(fmaf(v.y, s1, sh1), 0.f);
            v.z = fmaxf(fmaf(v.z, s1, sh1), 0.f);
            v.w = fmaxf(fmaf(v.w, s1, sh1), 0.f);
            *(float4*)&a1s[4 * tid] = v;
        }
        if (tid < 200) *(float4*)&w2s[4 * tid] = pw2;
        if (ic + 1 < 32) fetch(ic + 1);
        __builtin_amdgcn_sched_barrier(0);   // keep prefetch issued here (R4: it sank)
        __syncthreads();

#pragma unroll
        for (int kp = 0; kp < 12; ++kp) {
            const int k = kp * 2;
            float4 wA = *(const float4*)&w2s[k * 32 + oc0];
            float4 wB = *(const float4*)&w2s[(k + 1) * 32 + oc0];
            float x0[3], x1[3];
#pragma unroll
            for (int jt = 0; jt < 3; ++jt) {
                int a = 15 * tg + 5 * jt + k;
                x0[jt] = a1s[a]; x1[jt] = a1s[a + 1];
            }
            float wk[4]  = {wA.x, wA.y, wA.z, wA.w};
            float wk1[4] = {wB.x, wB.y, wB.z, wB.w};
#pragma unroll
            for (int jo = 0; jo < 4; ++jo)
#pragma unroll
                for (int jt = 0; jt < 3; ++jt)
                    acc[jo][jt] = fmaf(wk1[jo], x1[jt], fmaf(wk[jo], x0[jt], acc[jo][jt]));
        }
        {   // k = 24 tail
            float4 wT = *(const float4*)&w2s[24 * 32 + oc0];
            float wt[4] = {wT.x, wT.y, wT.z, wT.w};
#pragma unroll
            for (int jt = 0; jt < 3; ++jt) {
                float xt_ = a1s[15 * tg + 5 * jt + 24];
#pragma unroll
                for (int jo = 0; jo < 4; ++jo) acc[jo][jt] = fmaf(wt[jo], xt_, acc[jo][jt]);
            }
        }
        __syncthreads();   // a1s/w2s reusable next ic
    }

    float bias[4];
#pragma unroll
    for (int jo = 0; jo < 4; ++jo) bias[jo] = b2[oc0 + jo];

    float psum[4], psq[4];
#pragma unroll
    for (int jo = 0; jo < 4; ++jo) {
        float s = 0.f, q = 0.f;
#pragma unroll
        for (int jt = 0; jt < 3; ++jt) {
            int t2 = 3 * tg + jt;
            if (t2 < T2) {
                float v = acc[jo][jt] + bias[jo];
                y2[(size_t)b * 3040 + (oc0 + jo) * T2 + t2] = v;
                s += v; q = fmaf(v, v, q);
            }
        }
        psum[jo] = s; psq[jo] = q;
    }
#pragma unroll
    for (int off = 32; off >= 8; off >>= 1) {
#pragma unroll
        for (int jo = 0; jo < 4; ++jo) {
            psum[jo] += __shfl_down(psum[jo], off, 64);
            psq[jo]  += __shfl_down(psq[jo],  off, 64);
        }
    }
    int lane = tid & 63, wvi = tid >> 6;   // 4 waves
    if (lane < 8) {
#pragma unroll
        for (int jo = 0; jo < 4; ++jo) {
            sred[((wvi * 8 + lane) * 4 + jo) * 2 + 0] = psum[jo];
            sred[((wvi * 8 + lane) * 4 + jo) * 2 + 1] = psq[jo];
        }
    }
    __syncthreads();
    if (tid < 64) {
        int oc = tid >> 1, which = tid & 1;
        int og = oc >> 2, jo = oc & 3;
        float v = 0.f;
#pragma unroll
        for (int w = 0; w < 4; ++w)
            v += sred[((w * 8 + og) * 4 + jo) * 2 + which];
        atomicAdd(&stats[64 + which * 32 + oc], v);
    }
}

// ---------------- BN2-fold + projection + LN + PLRNN scan + out (fused) ----------------
// grid 512 (b), block 256. xs lives in LDS; scan runs in wave 0 with NO barriers
// (single-wave LDS ops are program-ordered; compiler inserts lgkmcnt waits).
__global__ __launch_bounds__(256, 2) void projscan_kernel(const float* __restrict__ g2,
                                                          const float* __restrict__ be2,
                                                          const float* __restrict__ pw,
                                                          const float* __restrict__ pb,
                                                          const float* __restrict__ lng,
                                                          const float* __restrict__ lnb,
                                                          const float* __restrict__ Am,
                                                          const float* __restrict__ Wm,
                                                          const float* __restrict__ hbp,
                                                          const float* __restrict__ ow,
                                                          const float* __restrict__ ob,
                                                          const float* __restrict__ ws,
                                                          float* __restrict__ out) {
    int b = blockIdx.x, tid = threadIdx.x;
    __shared__ float s2s[32], sh2s[32];
    __shared__ __align__(16) float a2s[3040];    // [f][t]
    __shared__ float pws[1056], ows[1056];       // [l][33]
    __shared__ __align__(16) float xsl[3135];    // [t][33]
    __shared__ __align__(16) float hs[32];
    __shared__ __align__(16) float hds[64];
    const float* stats = ws + OFS_STATS;
    const float* y2b = ws + OFS_Y2 + (size_t)b * 3040;

    if (tid < 32) {   // BN2 scale/shift in-kernel
        float mean = stats[64 + tid] * (1.f / 48640.f);
        float var  = stats[96 + tid] * (1.f / 48640.f) - mean * mean;
        float s = g2[tid] * rsqrtf(var + 1e-5f);
        s2s[tid] = s;
        sh2s[tid] = be2[tid] - mean * s;
    }
    for (int i = tid; i < 1024; i += 256) {
        pws[(i >> 5) * 33 + (i & 31)] = pw[i];
        ows[(i >> 5) * 33 + (i & 31)] = ow[i];
    }
    __syncthreads();

    for (int i = tid; i < 760; i += 256) {       // y2 -> BN2+ReLU -> a2s
        float4 v = *(const float4*)(y2b + 4 * i);
        float r[4] = {v.x, v.y, v.z, v.w};
        float o[4];
#pragma unroll
        for (int e = 0; e < 4; ++e) {
            int idx = 4 * i + e;
            int oc = idx / 95;
            o[e] = fmaxf(fmaf(r[e], s2s[oc], sh2s[oc]), 0.f);
        }
        float4 vv; vv.x = o[0]; vv.y = o[1]; vv.z = o[2]; vv.w = o[3];
        *(float4*)&a2s[4 * i] = vv;
    }
    __syncthreads();

    int l = tid & 31, ts = tid >> 5;
    {
        float pbv = pb[l], lg = lng[l], lb = lnb[l];
        for (int it = 0; it < 12; ++it) {
            int t = ts + 8 * it;
            if (t < T2) {
                float v = pbv;
#pragma unroll
                for (int f = 0; f < 32; ++f)
                    v = fmaf(a2s[f * T2 + t], pws[l * 33 + f], v);
                float sum = v;
#pragma unroll
                for (int off = 16; off >= 1; off >>= 1) sum += __shfl_xor(sum, off, 64);
                float mean = sum * (1.f / 32.f);
                float d = v - mean;
                float q = d * d;
#pragma unroll
                for (int off = 16; off >= 1; off >>= 1) q += __shfl_xor(q, off, 64);
                float o = d * rsqrtf(q * (1.f / 32.f) + 1e-5f) * lg + lb;
                xsl[t * 33 + l] = o;
            }
        }
    }
    __syncthreads();

    if (tid < 64) {   // scan: one wave, no barriers (intra-wave LDS ordering)
        int lane = tid, half = lane >> 5;
        float Wc[32], WT[32], Ah[16];
#pragma unroll
        for (int j = 0; j < 32; ++j) Wc[j] = Wm[j * 64 + lane];
#pragma unroll
        for (int m = 0; m < 32; ++m) WT[m] = Wm[l * 64 + half * 32 + m];
#pragma unroll
        for (int j = 0; j < 16; ++j) Ah[j] = Am[l * 32 + half * 16 + j];
        float hbv = hbp[lane];
        if (lane < 32) hs[l] = 0.f;
        float xv = xsl[l];
        float pool = 0.f;

        for (int t = 0; t < T2; ++t) {
            float4 hv[8];
#pragma unroll
            for (int q = 0; q < 8; ++q) hv[q] = *(const float4*)&hs[4 * q];
            float a0 = hbv, a1 = 0.f, a2 = 0.f, a3 = 0.f;
#pragma unroll
            for (int q = 0; q < 8; ++q) {
                a0 = fmaf(Wc[4 * q + 0], hv[q].x, a0);
                a1 = fmaf(Wc[4 * q + 1], hv[q].y, a1);
                a2 = fmaf(Wc[4 * q + 2], hv[q].z, a2);
                a3 = fmaf(Wc[4 * q + 3], hv[q].w, a3);
            }
            float hid = fmaxf((a0 + a1) + (a2 + a3), 0.f);
            float4 hl[4];
#pragma unroll
            for (int q = 0; q < 4; ++q) hl[q] = *(const float4*)&hs[half * 16 + 4 * q];
            float l0 = 0.f, l1 = 0.f;
#pragma unroll
            for (int q = 0; q < 4; ++q) {
                l0 = fmaf(Ah[4 * q + 0], hl[q].x, l0);
                l1 = fmaf(Ah[4 * q + 1], hl[q].y, l1);
                l0 = fmaf(Ah[4 * q + 2], hl[q].z, l0);
                l1 = fmaf(Ah[4 * q + 3], hl[q].w, l1);
            }
            float lin = l0 + l1;
            hds[lane] = hid;
            float n0 = 0.f, n1 = 0.f, n2 = 0.f, n3 = 0.f;
#pragma unroll
            for (int q = 0; q < 8; ++q) {
                float4 d4 = *(const float4*)&hds[half * 32 + 4 * q];
                n0 = fmaf(WT[4 * q + 0], d4.x, n0);
                n1 = fmaf(WT[4 * q + 1], d4.y, n1);
                n2 = fmaf(WT[4 * q + 2], d4.z, n2);
                n3 = fmaf(WT[4 * q + 3], d4.w, n3);
            }
            float part = (n0 + n1) + (n2 + n3) + lin;
            part += __shfl_xor(part, 32, 64);
            float hnew = part + xv;
            pool += hnew;
            if (t + 1 < T2) xv = xsl[(t + 1) * 33 + l];
            if (lane < 32) hs[l] = hnew;
        }

        if (lane < 32) hs[l] = pool * (1.f / 95.f);
        if (lane < 32) {
            float4 p0 = *(const float4*)&hs[0];
            float4 p1 = *(const float4*)&hs[4];
            float4 p2 = *(const float4*)&hs[8];
            float4 p3 = *(const float4*)&hs[12];
            float4 p4 = *(const float4*)&hs[16];
            float4 p5 = *(const float4*)&hs[20];
            float4 p6 = *(const float4*)&hs[24];
            float4 p7 = *(const float4*)&hs[28];
            float o = ob[l];
            const float* owr = &ows[l * 33];
            o = fmaf(owr[0],  p0.x, o); o = fmaf(owr[1],  p0.y, o);
            o = fmaf(owr[2],  p0.z, o); o = fmaf(owr[3],  p0.w, o);
            o = fmaf(owr[4],  p1.x, o); o = fmaf(owr[5],  p1.y, o);
            o = fmaf(owr[6],  p1.z, o); o = fmaf(owr[7],  p1.w, o);
            o = fmaf(owr[8],  p2.x, o); o = fmaf(owr[9],  p2.y, o);
            o = fmaf(owr[10], p2.z, o); o = fmaf(owr[11], p2.w, o);
            o = fmaf(owr[12], p3.x, o); o = fmaf(owr[13], p3.y, o);
            o = fmaf(owr[14], p3.z, o); o = fmaf(owr[15], p3.w, o);
            o = fmaf(owr[16], p4.x, o); o = fmaf(owr[17], p4.y, o);
            o = fmaf(owr[18], p4.z, o); o = fmaf(owr[19], p4.w, o);
            o = fmaf(owr[20], p5.x, o); o = fmaf(owr[21], p5.y, o);
            o = fmaf(owr[22], p5.z, o); o = fmaf(owr[23], p5.w, o);
            o = fmaf(owr[24], p6.x, o); o = fmaf(owr[25], p6.y, o);
            o = fmaf(owr[26], p6.z, o); o = fmaf(owr[27], p6.w, o);
            o = fmaf(owr[28], p7.x, o); o = fmaf(owr[29], p7.y, o);
            o = fmaf(owr[30], p7.z, o); o = fmaf(owr[31], p7.w, o);
            out[b * 32 + l] = o;
        }
    }
}

extern "C" void kernel_launch(void* const* d_in, const int* in_sizes, int n_in,
                              void* d_out, int out_size, void* d_ws, size_t ws_size,
                              hipStream_t stream) {
    (void)in_sizes; (void)n_in; (void)out_size; (void)ws_size;
    const float* x   = (const float*)d_in[0];
    const float* w1  = (const float*)d_in[1];
    const float* b1  = (const float*)d_in[2];
    const float* g1  = (const float*)d_in[3];
    const float* be1 = (const float*)d_in[4];
    const float* w2  = (const float*)d_in[5];
    const float* b2  = (const float*)d_in[6];
    const float* g2  = (const float*)d_in[7];
    const float* be2 = (const float*)d_in[8];
    const float* pw  = (const float*)d_in[9];
    const float* pb  = (const float*)d_in[10];
    const float* lng = (const float*)d_in[11];
    const float* lnb = (const float*)d_in[12];
    const float* Am  = (const float*)d_in[13];
    const float* Wm  = (const float*)d_in[14];
    const float* hb  = (const float*)d_in[15];
    const float* ow  = (const float*)d_in[16];
    const float* ob  = (const float*)d_in[17];
    float* ws  = (float*)d_ws;
    float* out = (float*)d_out;

    prep_kernel<<<176, 256, 0, stream>>>(w1, w2, ws);
    conv1_kernel<<<1024, 128, 0, stream>>>(x, b1, ws);
    conv2bn_kernel<<<512, 256, 0, stream>>>(g1, be1, b2, ws);
    projscan_kernel<<<512, 256, 0, stream>>>(g2, be2, pw, pb, lng, lnb,
                                             Am, Wm, hb, ow, ob, ws, out);
}